// Round 1
// 237.789 us; speedup vs baseline: 1.0366x; 1.0366x over previous
//
#include <hip/hip_runtime.h>
#include <math.h>

#define H 128
typedef unsigned int u32;
typedef unsigned long long u64;
typedef __attribute__((ext_vector_type(8))) short short8;
typedef __attribute__((ext_vector_type(4))) float floatx4;

#define XS_STRIDE 136   // bf16 elems per padded row (128 + 8)

#define SCAN_B 64
#define SCAN_T 256

__device__ __forceinline__ float sigmoid_f(float x) {
    return 1.0f / (1.0f + __expf(-x));
}
__device__ __forceinline__ float tanh_f(float x) {
    float t = __expf(-2.0f * fabsf(x));
    float r = (1.0f - t) / (1.0f + t);
    return copysignf(r, x);
}
// f32 -> bf16 bits, round-to-nearest-even (finite inputs)
__device__ __forceinline__ unsigned short f2bf(float x) {
    u32 u = __float_as_uint(x);
    return (unsigned short)((u + 0x7fffu + ((u >> 16) & 1u)) >> 16);
}
__device__ __forceinline__ float bf2f(unsigned short s) {
    return __uint_as_float(((u32)s) << 16);
}
__device__ __forceinline__ float bf_lo32(u32 u) { return __uint_as_float(u << 16); }
__device__ __forceinline__ float bf_hi32(u32 u) { return __uint_as_float(u & 0xffff0000u); }

// ---------------------------------------------------------------------------
// h (f32) -> h_b (bf16), streaming. One thread = 8 elements.
// ---------------------------------------------------------------------------
__global__ __launch_bounds__(256) void h_convert_kernel(
    const float* __restrict__ h, unsigned short* __restrict__ h_b, int total8)
{
    int idx = blockIdx.x * 256 + threadIdx.x;
    if (idx >= total8) return;
    const float4* p = (const float4*)(h + (size_t)idx * 8);
    float4 a = p[0], b = p[1];
    short8 v;
    v[0] = (short)f2bf(a.x); v[1] = (short)f2bf(a.y);
    v[2] = (short)f2bf(a.z); v[3] = (short)f2bf(a.w);
    v[4] = (short)f2bf(b.x); v[5] = (short)f2bf(b.y);
    v[6] = (short)f2bf(b.z); v[7] = (short)f2bf(b.w);
    *(short8*)(h_b + (size_t)idx * 8) = v;
}

// ---------------------------------------------------------------------------
// Prep: fold the message GEMM into the GRU input weights.
//   W_c[g][k]   = sum_c W_ih[g][c] * W_m[c][k]       (384x128, f32 -> bf16 swz)
//   embW'[t][g] = sum_j (emb[t][j]+bm[j]) * W_ih[g][j]  (9x384, swz K=32 frag)
//   Whh         -> Whhs (swizzled bf16, as before)
// Swizzle (B-frag, 16x16x32): frag[((gtile*4+kc)*64 + l)*8 + i] =
//   W[(gtile*16 + (l&15))][kc*32 + (l>>4)*8 + i]
// ---------------------------------------------------------------------------
__global__ __launch_bounds__(256) void prep_kernel(
    const float* __restrict__ Wih, const float* __restrict__ Whh,
    const float* __restrict__ Wm,  const float* __restrict__ emb,
    const float* __restrict__ bm,
    unsigned short* __restrict__ Wcs, unsigned short* __restrict__ Whhs,
    unsigned short* __restrict__ embWs)
{
    int idx = blockIdx.x * 256 + threadIdx.x;
    if (idx < 49152) {
        // ---- W_c: one thread per (g,k); lanes span k -> Wm rows coalesced,
        //      Wih[g][c] wave-uniform.
        int g = idx >> 7;          // 0..383 (output row of gi)
        int k = idx & 127;         // input feature (h-space)
        float acc = 0.f;
#pragma unroll 4
        for (int c = 0; c < H; ++c)
            acc += Wih[(size_t)g * H + c] * Wm[(size_t)c * H + k];
        int gate = g >> 7;         // 0..2
        int wi = g & 127;
        int j = wi >> 4, m = wi & 15;
        int kc = k >> 5, q = (k >> 3) & 3, i = k & 7;
        int l = q * 16 + m;
        Wcs[(size_t)(((gate * 8 + j) * 4 + kc) * 64 + l) * 8 + i] = f2bf(acc);
    } else if (idx < 61440) {
        // ---- embW' directly into its swizzled K=32 fragment (zeros for t>=9)
        int s = idx - 49152;       // 0..12287 == frag linear index
        int i = s & 7;
        int l = (s >> 3) & 63;
        int jb = s >> 9;           // 0..23 == gate*8 + j
        int gate = jb >> 3, jj = jb & 7;
        int q = l >> 4, m = l & 15;
        int t = q * 8 + i;         // edge type (K index)
        unsigned short v = 0;
        if (t < 9) {
            int g = gate * 128 + jj * 16 + m;   // output row of gi
            float acc = 0.f;
#pragma unroll 4
            for (int jx = 0; jx < H; ++jx)
                acc += (emb[(size_t)t * H + jx] + bm[jx]) * Wih[(size_t)g * H + jx];
            v = f2bf(acc);
        }
        embWs[s] = v;
    } else if (idx < 67584) {
        // ---- Whh convert + swizzle (same layout as before)
        int t2 = idx - 61440;      // 0..6143
        int l  = t2 & 63;
        int kc = (t2 >> 6) & 3;
        int jr = t2 >> 8;          // 0..23 == gate*8 + j
        int m = l & 15, q = l >> 4;
        size_t srco = (size_t)(jr * 16 + m) * H + kc * 32 + q * 8;
        const float4* s0 = (const float4*)(Whh + srco);
        float4 a = s0[0], b = s0[1];
        short8 v;
        v[0] = (short)f2bf(a.x); v[1] = (short)f2bf(a.y);
        v[2] = (short)f2bf(a.z); v[3] = (short)f2bf(a.w);
        v[4] = (short)f2bf(b.x); v[5] = (short)f2bf(b.y);
        v[6] = (short)f2bf(b.z); v[7] = (short)f2bf(b.w);
        *(short8*)(Whhs + (size_t)t2 * 8) = v;
    }
}

// ---------------------------------------------------------------------------
// CSR build step 1: degree histogram over dst.
// ---------------------------------------------------------------------------
__global__ __launch_bounds__(256) void hist_kernel(
    const int* __restrict__ eidx, int* __restrict__ deg, int E)
{
    int e = blockIdx.x * 256 + threadIdx.x;
    if (e < E) atomicAdd(&deg[eidx[E + e]], 1);
}

// ---------------------------------------------------------------------------
// CSR build step 2a: per-thread chunk sums + per-block totals (parallel).
// ---------------------------------------------------------------------------
__global__ __launch_bounds__(SCAN_T) void scan_part_kernel(
    const int* __restrict__ deg, int* __restrict__ tsum,
    int* __restrict__ bsum, int N, int ipt)
{
    __shared__ int red[SCAN_T];
    int t = threadIdx.x;
    int g = blockIdx.x * SCAN_T + t;
    int s = g * ipt;
    int e = s + ipt < N ? s + ipt : N;
    int sum = 0;
    for (int i = s; i < e; ++i) sum += deg[i];
    tsum[g] = sum;
    red[t] = sum;
    __syncthreads();
    for (int d = SCAN_T / 2; d > 0; d >>= 1) {
        if (t < d) red[t] += red[t + d];
        __syncthreads();
    }
    if (t == 0) bsum[blockIdx.x] = red[0];
}

// ---------------------------------------------------------------------------
// CSR build step 2b (merged): per-block scan of raw bsum + thread sums,
// then write off/pos. Block 0 also writes off[N].
// ---------------------------------------------------------------------------
__global__ __launch_bounds__(SCAN_T) void scan_final_kernel(
    const int* __restrict__ deg, const int* __restrict__ tsum,
    const int* __restrict__ bsum, int* __restrict__ off,
    int* __restrict__ pos, int N, int ipt)
{
    __shared__ int part[SCAN_T];
    __shared__ int bpre[SCAN_B + 1];
    int t = threadIdx.x;
    if (t == 0) {
        int acc = 0;
        for (int b2 = 0; b2 < SCAN_B; ++b2) { bpre[b2] = acc; acc += bsum[b2]; }
        bpre[SCAN_B] = acc;
        if (blockIdx.x == 0) off[N] = acc;
    }
    int g = blockIdx.x * SCAN_T + t;
    part[t] = tsum[g];
    __syncthreads();
    for (int d = 1; d < SCAN_T; d <<= 1) {
        int v = (t >= d) ? part[t - d] : 0;
        __syncthreads();
        part[t] += v;
        __syncthreads();
    }
    int base = bpre[blockIdx.x] + ((t == 0) ? 0 : part[t - 1]);
    int s = g * ipt;
    int e = s + ipt < N ? s + ipt : N;
    for (int i = s; i < e; ++i) {
        off[i] = base;
        pos[i] = base;
        base += deg[i];
    }
}

// ---------------------------------------------------------------------------
// CSR build step 3: scatter edge ids into slots; pack src|type into one int.
// ---------------------------------------------------------------------------
__global__ __launch_bounds__(256) void fill_kernel(
    const int* __restrict__ eidx, const int* __restrict__ etype,
    int* __restrict__ pos, int* __restrict__ packed, int E)
{
    int e = blockIdx.x * 256 + threadIdx.x;
    if (e >= E) return;
    int src = eidx[e];
    int dst = eidx[E + e];
    int t = etype[e];
    t = t < 0 ? 0 : (t > 8 ? 8 : t);
    int p = atomicAdd(&pos[dst], 1);
    packed[p] = src | (t << 24);
}

// ---------------------------------------------------------------------------
// Gather: S[n] = sum_{e: dst=n} h_b[src_e]  (raw h-space sum, f32 acc ->
// bf16), plus packed 7-bit per-type counters -> cnt[n] (u64).
// No per-edge GEMM needed anymore (folded into W_c / embW').
// ---------------------------------------------------------------------------
__global__ __launch_bounds__(256) void gather_kernel(
    const unsigned short* __restrict__ h_b,
    const int* __restrict__ off, const int* __restrict__ packed,
    unsigned short* __restrict__ S_b, u64* __restrict__ cnt, int N)
{
    int n = blockIdx.x * 4 + (threadIdx.x >> 6);
    if (n >= N) return;
    int lane = threadIdx.x & 63;
    int b = off[n], e = off[n + 1];
    float ax = 0.f, ay = 0.f;
    u64 c = 0;
    int i = b;
    for (; i + 4 <= e; i += 4) {
        int u0 = packed[i + 0];
        int u1 = packed[i + 1];
        int u2 = packed[i + 2];
        int u3 = packed[i + 3];
        u32 x0 = *((const u32*)(h_b + (size_t)(u0 & 0xffffff) * H) + lane);
        u32 x1 = *((const u32*)(h_b + (size_t)(u1 & 0xffffff) * H) + lane);
        u32 x2 = *((const u32*)(h_b + (size_t)(u2 & 0xffffff) * H) + lane);
        u32 x3 = *((const u32*)(h_b + (size_t)(u3 & 0xffffff) * H) + lane);
        c += (1ull << (7 * (u0 >> 24))) + (1ull << (7 * (u1 >> 24)))
           + (1ull << (7 * (u2 >> 24))) + (1ull << (7 * (u3 >> 24)));
        ax += bf_lo32(x0) + bf_lo32(x1) + bf_lo32(x2) + bf_lo32(x3);
        ay += bf_hi32(x0) + bf_hi32(x1) + bf_hi32(x2) + bf_hi32(x3);
    }
    for (; i < e; ++i) {
        int u = packed[i];
        u32 x = *((const u32*)(h_b + (size_t)(u & 0xffffff) * H) + lane);
        c += 1ull << (7 * (u >> 24));
        ax += bf_lo32(x);
        ay += bf_hi32(x);
    }
    u32 o = (u32)f2bf(ax) | ((u32)f2bf(ay) << 16);
    *((u32*)(S_b + (size_t)n * H) + lane) = o;
    if (lane == 0) cnt[n] = c;
}

// ---------------------------------------------------------------------------
// Fused GRU (MFMA), 32-node tiles; wave = (row half, j half).
//   gi = S @ W_c^T + counts @ embW' + b_ih     (x side: 4 MFMA sets + 1 emb)
//   gh = h @ Whh^T + b_hh                      (h side: unchanged)
// counts staged as a 32x32 bf16 LDS tile (types 0..8, zero-padded K=32).
// ---------------------------------------------------------------------------
__global__ __launch_bounds__(256, 4) void gru_mfma_kernel(
    const unsigned short* __restrict__ S_b, const unsigned short* __restrict__ h_b,
    const unsigned short* __restrict__ Wcs, const unsigned short* __restrict__ Whhs,
    const unsigned short* __restrict__ embWs,
    const float* __restrict__ bih, const float* __restrict__ bhh,
    const u64* __restrict__ cnt,
    const int* __restrict__ numn, float* __restrict__ out, int N)
{
    __shared__ unsigned short xs[32 * XS_STRIDE];
    __shared__ unsigned short hsb[32 * XS_STRIDE];
    __shared__ unsigned short cs[32 * 32];

    int tid = threadIdx.x;
    int node0 = blockIdx.x * 32;

    for (int c = tid; c < 512; c += 256) {
        int r = c >> 4;
        int k8 = (c & 15) << 3;
        int n = node0 + r;
        int nc = n < N ? n : N - 1;
        *(short8*)(&xs[r * XS_STRIDE + k8]) =
            *(const short8*)(S_b + (size_t)nc * H + k8);
        *(short8*)(&hsb[r * XS_STRIDE + k8]) =
            *(const short8*)(h_b + (size_t)nc * H + k8);
    }
    for (int c2 = tid; c2 < 1024; c2 += 256) {
        int r = c2 >> 5, t = c2 & 31;
        int n = node0 + r;
        u64 cv = cnt[n < N ? n : N - 1];
        cs[c2] = (t < 9) ? f2bf((float)((u32)(cv >> (7 * t)) & 127u))
                         : (unsigned short)0;
    }
    __syncthreads();

    int lane = tid & 63;
    int wv = tid >> 6;
    int rg = wv & 1;
    int jhalf = wv >> 1;
    int am = lane & 15;
    int aq = lane >> 4;

    short8 ax[4], ahf[4];
    int arow = rg * 16 + am;
#pragma unroll
    for (int kc = 0; kc < 4; ++kc) {
        ax[kc]  = *(const short8*)(&xs[arow * XS_STRIDE + kc * 32 + aq * 8]);
        ahf[kc] = *(const short8*)(&hsb[arow * XS_STRIDE + kc * 32 + aq * 8]);
    }
    short8 acn = *(const short8*)(&cs[arow * 32 + aq * 8]);

    int num_nodes = numn[0];
    floatx4 zero = {0.f, 0.f, 0.f, 0.f};

#pragma unroll
    for (int jt = 0; jt < 4; ++jt) {
        int j = jhalf * 4 + jt;
        floatx4 aIr = zero, aHr = zero, aIz = zero, aHz = zero, aIn = zero, aHn = zero;
        // emb/bias-msg contribution: rank-32 counts MFMA, one per gate
        {
            short8 er = *(const short8*)(embWs + (size_t)((0 * 8 + j) * 64 + lane) * 8);
            short8 ez = *(const short8*)(embWs + (size_t)((1 * 8 + j) * 64 + lane) * 8);
            short8 en = *(const short8*)(embWs + (size_t)((2 * 8 + j) * 64 + lane) * 8);
            aIr = __builtin_amdgcn_mfma_f32_16x16x32_bf16(acn, er, aIr, 0, 0, 0);
            aIz = __builtin_amdgcn_mfma_f32_16x16x32_bf16(acn, ez, aIz, 0, 0, 0);
            aIn = __builtin_amdgcn_mfma_f32_16x16x32_bf16(acn, en, aIn, 0, 0, 0);
        }
#pragma unroll
        for (int kc = 0; kc < 4; ++kc) {
            size_t c_r = (size_t)(((0 * 8 + j) * 4 + kc) * 64 + lane) * 8;
            size_t c_z = (size_t)(((1 * 8 + j) * 4 + kc) * 64 + lane) * 8;
            size_t c_n = (size_t)(((2 * 8 + j) * 4 + kc) * 64 + lane) * 8;
            short8 bir = *(const short8*)(Wcs + c_r);
            short8 bhr = *(const short8*)(Whhs + c_r);
            short8 biz = *(const short8*)(Wcs + c_z);
            short8 bhz = *(const short8*)(Whhs + c_z);
            short8 bin = *(const short8*)(Wcs + c_n);
            short8 bhn = *(const short8*)(Whhs + c_n);
            aIr = __builtin_amdgcn_mfma_f32_16x16x32_bf16(ax[kc],  bir, aIr, 0, 0, 0);
            aHr = __builtin_amdgcn_mfma_f32_16x16x32_bf16(ahf[kc], bhr, aHr, 0, 0, 0);
            aIz = __builtin_amdgcn_mfma_f32_16x16x32_bf16(ax[kc],  biz, aIz, 0, 0, 0);
            aHz = __builtin_amdgcn_mfma_f32_16x16x32_bf16(ahf[kc], bhz, aHz, 0, 0, 0);
            aIn = __builtin_amdgcn_mfma_f32_16x16x32_bf16(ax[kc],  bin, aIn, 0, 0, 0);
            aHn = __builtin_amdgcn_mfma_f32_16x16x32_bf16(ahf[kc], bhn, aHn, 0, 0, 0);
        }
        int c = j * 16 + am;
        float b_ir = bih[c],       b_hr = bhh[c];
        float b_iz = bih[128 + c], b_hz = bhh[128 + c];
        float b_in = bih[256 + c], b_hn = bhh[256 + c];
#pragma unroll
        for (int q = 0; q < 4; ++q) {
            int m = aq * 4 + q;
            int node = node0 + rg * 16 + m;
            if (node < N) {
                float r  = sigmoid_f(aIr[q] + b_ir + aHr[q] + b_hr);
                float z  = sigmoid_f(aIz[q] + b_iz + aHz[q] + b_hz);
                float nv = tanh_f((aIn[q] + b_in) + r * (aHn[q] + b_hn));
                float hv = bf2f(hsb[(rg * 16 + m) * XS_STRIDE + c]);
                float o  = (1.0f - z) * nv + z * hv;
                out[(size_t)node * H + c] = (node < num_nodes) ? o : 0.0f;
            }
        }
    }
}

extern "C" void kernel_launch(void* const* d_in, const int* in_sizes, int n_in,
                              void* d_out, int out_size, void* d_ws, size_t ws_size,
                              hipStream_t stream) {
    const float* h    = (const float*)d_in[0];
    const int*  eidx  = (const int*)d_in[1];
    const int*  etype = (const int*)d_in[2];
    const int*  numn  = (const int*)d_in[3];
    const float* Wm   = (const float*)d_in[4];
    const float* bm   = (const float*)d_in[5];
    const float* emb  = (const float*)d_in[6];
    const float* Wih  = (const float*)d_in[7];
    const float* Whh  = (const float*)d_in[8];
    const float* bih  = (const float*)d_in[9];
    const float* bhh  = (const float*)d_in[10];

    int N = in_sizes[0] / H;
    int E = in_sizes[2];

    // ws layout:
    unsigned short* S_b   = (unsigned short*)d_ws;               // N*H bf16
    unsigned short* h_b   = S_b + (size_t)N * H;                 // N*H bf16
    unsigned short* Wcs   = h_b + (size_t)N * H;                 // 3*H*H (swizzled)
    unsigned short* Whhs  = Wcs + 3 * H * H;                     // 3*H*H (swizzled)
    unsigned short* embWs = Whhs + 3 * H * H;                    // 3*8*64*8 = 12288
    u64* cnt    = (u64*)(embWs + 12288);                         // N (8B-aligned)
    int* deg    = (int*)(cnt + N);                               // N
    int* pos    = deg + N;                                       // N
    int* off    = pos + N;                                       // N+1
    int* packed = off + (N + 1);                                 // E
    int* tsum   = packed + E;                                    // SCAN_B*SCAN_T
    int* bsum   = tsum + SCAN_B * SCAN_T;                        // SCAN_B

    hipMemsetAsync(deg, 0, (size_t)N * sizeof(int), stream);

    int total8 = N * H / 8;
    h_convert_kernel<<<(total8 + 255) / 256, 256, 0, stream>>>(h, h_b, total8);
    prep_kernel<<<264, 256, 0, stream>>>(Wih, Whh, Wm, emb, bm, Wcs, Whhs, embWs);
    hist_kernel<<<(E + 255) / 256, 256, 0, stream>>>(eidx, deg, E);

    int ipt = (N + SCAN_B * SCAN_T - 1) / (SCAN_B * SCAN_T);
    scan_part_kernel<<<SCAN_B, SCAN_T, 0, stream>>>(deg, tsum, bsum, N, ipt);
    scan_final_kernel<<<SCAN_B, SCAN_T, 0, stream>>>(deg, tsum, bsum, off, pos, N, ipt);

    fill_kernel<<<(E + 255) / 256, 256, 0, stream>>>(eidx, etype, pos, packed, E);

    gather_kernel<<<(N + 3) / 4, 256, 0, stream>>>(h_b, off, packed, S_b, cnt, N);

    int nblk32 = (N + 31) / 32;
    gru_mfma_kernel<<<nblk32, 256, 0, stream>>>(S_b, h_b, Wcs, Whhs, embWs,
                                                bih, bhh, cnt, numn, (float*)d_out, N);
}